// Round 1
// baseline (541.156 us; speedup 1.0000x reference)
//
#include <hip/hip_runtime.h>
#include <cmath>

typedef unsigned short u16;
typedef __attribute__((ext_vector_type(8))) short short8;
typedef __attribute__((ext_vector_type(4))) float f32x4;
typedef __attribute__((ext_vector_type(4))) unsigned short u16x4;

#define AT_B 2
#define AT_T 2048
#define AT_H 16
#define AT_D 128
#define AT_M 2048
#define NROW (AT_B*AT_T)   // 4096
#define HD   (AT_H*AT_D)   // 2048

__device__ __forceinline__ u16 f2bf(float f) {
    union { float f; unsigned u; } v; v.f = f;
    unsigned u = v.u;
    unsigned r = u + 0x7fffu + ((u >> 16) & 1u);
    return (u16)(r >> 16);
}
__device__ __forceinline__ float bf2f(u16 h) {
    union { unsigned u; float f; } v; v.u = ((unsigned)h) << 16;
    return v.f;
}

// ---------------- elementwise cast fp32 -> bf16 (vec4) ----------------
__global__ void cast_bf16_k(const float* __restrict__ in, u16* __restrict__ out, int n4) {
    int i = blockIdx.x * 256 + threadIdx.x;
    if (i >= n4) return;
    float4 v = ((const float4*)in)[i];
    u16x4 o;
    o.x = f2bf(v.x); o.y = f2bf(v.y); o.z = f2bf(v.z); o.w = f2bf(v.w);
    ((u16x4*)out)[i] = o;
}

// ------------- batched transpose-cast: in[bz][R][C] fp32 -> out[bz][C][R] bf16 -------------
__global__ void tcast_k(const float* __restrict__ in, u16* __restrict__ out, int R, int C) {
    __shared__ float tile[32][33];
    int bx = blockIdx.x, by = blockIdx.y, bz = blockIdx.z;
    const float* ip = in + (size_t)bz * R * C;
    u16* op = out + (size_t)bz * R * C;
    int tx = threadIdx.x, ty = threadIdx.y;
    #pragma unroll
    for (int j = 0; j < 32; j += 8)
        tile[ty + j][tx] = ip[(size_t)(by * 32 + ty + j) * C + bx * 32 + tx];
    __syncthreads();
    #pragma unroll
    for (int j = 0; j < 32; j += 8)
        op[(size_t)(bx * 32 + ty + j) * R + by * 32 + tx] = f2bf(tile[tx][ty + j]);
}

// ------------- batched transpose bf16 -> bf16: in[bz][R][C] -> out[bz][C][R] -------------
__global__ void tbf16_k(const u16* __restrict__ in, u16* __restrict__ out, int R, int C) {
    __shared__ u16 tile[32][33];
    int bx = blockIdx.x, by = blockIdx.y, bz = blockIdx.z;
    const u16* ip = in + (size_t)bz * R * C;
    u16* op = out + (size_t)bz * R * C;
    int tx = threadIdx.x, ty = threadIdx.y;
    #pragma unroll
    for (int j = 0; j < 32; j += 8)
        tile[ty + j][tx] = ip[(size_t)(by * 32 + ty + j) * C + bx * 32 + tx];
    __syncthreads();
    #pragma unroll
    for (int j = 0; j < 32; j += 8)
        op[(size_t)(bx * 32 + ty + j) * R + by * 32 + tx] = tile[tx][ty + j];
}

// ---------------- RoPE in place on q and k (bf16, pair d / d+64) ----------------
__global__ void rope_k(u16* __restrict__ q, u16* __restrict__ k, int total) {
    int i = blockIdx.x * 256 + threadIdx.x;
    if (i >= total) return;
    int d = i & 63;
    int rest = i >> 6;                 // (b*T+t)*H + h
    int t = (rest >> 4) & (AT_T - 1);
    size_t base = (size_t)rest * 128;
    float freq = __expf(-(float)d * (9.210340371976184f / 64.0f)); // 10000^{-d/64}
    float ang = (float)t * freq;
    float s, c;
    sincosf(ang, &s, &c);
    float qe = bf2f(q[base + d]), qo = bf2f(q[base + d + 64]);
    q[base + d]      = f2bf(qe * c - qo * s);
    q[base + d + 64] = f2bf(qe * s + qo * c);
    float ke = bf2f(k[base + d]), ko = bf2f(k[base + d + 64]);
    k[base + d]      = f2bf(ke * c - ko * s);
    k[base + d + 64] = f2bf(ke * s + ko * c);
}

// ---------------- GEMM: C[M][N] = A[M][K] * Bt[N][K]^T  (bf16 in, fp32 acc) ----------------
// m97 structure: 128x128 tile, BK=64, 4 waves each 64x64, global_load_lds width 16.
template<int FP32OUT>
__global__ __launch_bounds__(256, 2) void gemm_bt_k(
    const u16* __restrict__ A, const u16* __restrict__ Bt, void* __restrict__ Cv,
    int M, int N, int K)
{
    __shared__ u16 As[128 * 64];
    __shared__ u16 Bs[128 * 64];
    const int tid = threadIdx.x, wave = tid >> 6, lane = tid & 63;
    const int quad = lane >> 4, l16 = lane & 15;
    const int m0 = blockIdx.y * 128, n0 = blockIdx.x * 128;
    const int mw = (wave & 1) * 64, nw = (wave >> 1) * 64;

    f32x4 zero = {0.f, 0.f, 0.f, 0.f};
    f32x4 acc[4][4];
    #pragma unroll
    for (int i = 0; i < 4; i++)
        #pragma unroll
        for (int j = 0; j < 4; j++) acc[i][j] = zero;

    const int srow = (lane >> 3);    // 0..7
    const int scol = (lane & 7) * 8; // ushort col within BK

    for (int kk = 0; kk < K; kk += 64) {
        #pragma unroll
        for (int c = 0; c < 4; c++) {
            int ci = wave * 4 + c;
            const u16* ga = A  + (size_t)(m0 + ci * 8 + srow) * K + kk + scol;
            const u16* gb = Bt + (size_t)(n0 + ci * 8 + srow) * K + kk + scol;
            __builtin_amdgcn_global_load_lds((const __attribute__((address_space(1))) void*)ga,
                                             (__attribute__((address_space(3))) void*)&As[ci * 512], 16, 0, 0);
            __builtin_amdgcn_global_load_lds((const __attribute__((address_space(1))) void*)gb,
                                             (__attribute__((address_space(3))) void*)&Bs[ci * 512], 16, 0, 0);
        }
        __syncthreads();
        #pragma unroll
        for (int ks = 0; ks < 2; ks++) {
            short8 af[4], bfr[4];
            #pragma unroll
            for (int mf = 0; mf < 4; mf++)
                af[mf] = *(const short8*)&As[(mw + mf * 16 + l16) * 64 + ks * 32 + quad * 8];
            #pragma unroll
            for (int nf = 0; nf < 4; nf++)
                bfr[nf] = *(const short8*)&Bs[(nw + nf * 16 + l16) * 64 + ks * 32 + quad * 8];
            #pragma unroll
            for (int mf = 0; mf < 4; mf++)
                #pragma unroll
                for (int nf = 0; nf < 4; nf++)
                    acc[mf][nf] = __builtin_amdgcn_mfma_f32_16x16x32_bf16(af[mf], bfr[nf], acc[mf][nf], 0, 0, 0);
        }
        __syncthreads();
    }
    // epilogue: C layout col=lane&15, row=quad*4+reg
    #pragma unroll
    for (int mf = 0; mf < 4; mf++)
        #pragma unroll
        for (int nf = 0; nf < 4; nf++)
            #pragma unroll
            for (int r = 0; r < 4; r++) {
                int row = m0 + mw + mf * 16 + quad * 4 + r;
                int col = n0 + nw + nf * 16 + l16;
                if (FP32OUT) ((float*)Cv)[(size_t)row * N + col] = acc[mf][nf][r];
                else         ((u16*) Cv)[(size_t)row * N + col] = f2bf(acc[mf][nf][r]);
            }
}

// ---------------- Flash attention, causal, bf16 in/out ----------------
// grid (T/128, H, B), 256 threads. q,k: [B,T,H,D]; vt: [B,H,D,T]; o: [B,T,H,D]
__global__ __launch_bounds__(256, 1) void attn_k(
    const u16* __restrict__ q, const u16* __restrict__ k,
    const u16* __restrict__ vt, u16* __restrict__ o)
{
    __shared__ __align__(16) u16 Ks[128 * 136];  // K tile (also reused as P buffer)
    __shared__ __align__(16) u16 Vs[128 * 72];   // V half-tile: [d=128][64 keys], pad 8
    const int tid = threadIdx.x, wave = tid >> 6, lane = tid & 63;
    const int quad = lane >> 4, l16 = lane & 15;
    const int qt = blockIdx.x, h = blockIdx.y, b = blockIdx.z;

    // ---- stage Q tile into Ks, pull Q fragments to registers ----
    #pragma unroll
    for (int it = 0; it < 8; ++it) {
        int vid = it * 256 + tid;
        int row = vid >> 4, c8 = vid & 15;
        *(short8*)&Ks[row * 136 + c8 * 8] =
            *(const short8*)(q + ((size_t)((b * AT_T + qt * 128 + row) * AT_H) + h) * 128 + c8 * 8);
    }
    __syncthreads();
    short8 qf[2][4];
    #pragma unroll
    for (int mf = 0; mf < 2; mf++)
        #pragma unroll
        for (int ks = 0; ks < 4; ks++)
            qf[mf][ks] = *(const short8*)&Ks[(wave * 32 + mf * 16 + l16) * 136 + ks * 32 + quad * 8];
    __syncthreads();

    f32x4 zero = {0.f, 0.f, 0.f, 0.f};
    f32x4 Oacc[2][8];
    #pragma unroll
    for (int i = 0; i < 2; i++)
        #pragma unroll
        for (int j = 0; j < 8; j++) Oacc[i][j] = zero;
    float m_i[8], l_i[8];
    #pragma unroll
    for (int i = 0; i < 8; i++) { m_i[i] = -1e30f; l_i[i] = 0.f; }

    u16* Ps = &Ks[wave * 32 * 136];  // per-wave P region (overlaps Ks)

    for (int kt = 0; kt <= qt; ++kt) {
        // stage K tile [128 keys][128 d] (pad 136)
        #pragma unroll
        for (int it = 0; it < 8; ++it) {
            int vid = it * 256 + tid;
            int row = vid >> 4, c8 = vid & 15;
            *(short8*)&Ks[row * 136 + c8 * 8] =
                *(const short8*)(k + ((size_t)((b * AT_T + kt * 128 + row) * AT_H) + h) * 128 + c8 * 8);
        }
        // stage V half 0: Vs[d][key 0..63]
        #pragma unroll
        for (int it = 0; it < 4; ++it) {
            int vid = it * 256 + tid;
            int d = vid >> 3, c8 = vid & 7;
            *(short8*)&Vs[d * 72 + c8 * 8] =
                *(const short8*)(vt + ((size_t)(b * AT_H + h) * 128 + d) * AT_T + kt * 128 + c8 * 8);
        }
        __syncthreads();  // (A) staging visible

        // ---- S = Q K^T ----
        f32x4 Sacc[2][8];
        #pragma unroll
        for (int i = 0; i < 2; i++)
            #pragma unroll
            for (int j = 0; j < 8; j++) Sacc[i][j] = zero;
        #pragma unroll
        for (int nf = 0; nf < 8; nf++) {
            short8 bfr[4];
            #pragma unroll
            for (int ks = 0; ks < 4; ks++)
                bfr[ks] = *(const short8*)&Ks[(nf * 16 + l16) * 136 + ks * 32 + quad * 8];
            #pragma unroll
            for (int mf = 0; mf < 2; mf++)
                #pragma unroll
                for (int ks = 0; ks < 4; ks++)
                    Sacc[mf][nf] = __builtin_amdgcn_mfma_f32_16x16x32_bf16(qf[mf][ks], bfr[ks], Sacc[mf][nf], 0, 0, 0);
        }

        // ---- online softmax (C layout: lane owns col=l16+16nf of rows quad*4+r) ----
        float alpha[8];
        #pragma unroll
        for (int mf = 0; mf < 2; mf++)
            #pragma unroll
            for (int r = 0; r < 4; r++) {
                int idx = mf * 4 + r;
                int ig = qt * 128 + wave * 32 + mf * 16 + quad * 4 + r;
                float mx = -1e30f;
                #pragma unroll
                for (int nf = 0; nf < 8; nf++) {
                    int jg = kt * 128 + nf * 16 + l16;
                    float s = Sacc[mf][nf][r] * (1.0f / 128.0f);
                    if (jg > ig) s = -1e30f;
                    Sacc[mf][nf][r] = s;
                    mx = fmaxf(mx, s);
                }
                #pragma unroll
                for (int mk = 1; mk < 16; mk <<= 1) mx = fmaxf(mx, __shfl_xor(mx, mk, 64));
                float mnew = fmaxf(m_i[idx], mx);
                alpha[idx] = __expf(m_i[idx] - mnew);
                m_i[idx] = mnew;
                float rs = 0.f;
                #pragma unroll
                for (int nf = 0; nf < 8; nf++) {
                    float p = __expf(Sacc[mf][nf][r] - mnew);
                    Sacc[mf][nf][r] = p;
                    rs += p;
                }
                #pragma unroll
                for (int mk = 1; mk < 16; mk <<= 1) rs += __shfl_xor(rs, mk, 64);
                l_i[idx] = l_i[idx] * alpha[idx] + rs;
            }
        // rescale O accumulator
        #pragma unroll
        for (int mf = 0; mf < 2; mf++)
            #pragma unroll
            for (int nf = 0; nf < 8; nf++)
                #pragma unroll
                for (int r = 0; r < 4; r++) Oacc[mf][nf][r] *= alpha[mf * 4 + r];

        __syncthreads();  // (A2) all waves done reading Ks before P overwrites it

        // write P (bf16) into own-wave region of Ks
        #pragma unroll
        for (int mf = 0; mf < 2; mf++)
            #pragma unroll
            for (int nf = 0; nf < 8; nf++)
                #pragma unroll
                for (int r = 0; r < 4; r++)
                    Ps[(mf * 16 + quad * 4 + r) * 136 + nf * 16 + l16] = f2bf(Sacc[mf][nf][r]);
        __syncthreads();  // (A3) P visible (also forces write->read ordering)

        // load P A-fragments (full 128 key cols)
        short8 pf[2][4];
        #pragma unroll
        for (int mf = 0; mf < 2; mf++)
            #pragma unroll
            for (int ks = 0; ks < 4; ks++)
                pf[mf][ks] = *(const short8*)&Ps[(mf * 16 + l16) * 136 + ks * 32 + quad * 8];

        // ---- PV half 0 (keys 0..63) ----
        #pragma unroll
        for (int nf = 0; nf < 8; nf++) {
            short8 vf[2];
            #pragma unroll
            for (int ks = 0; ks < 2; ks++)
                vf[ks] = *(const short8*)&Vs[(nf * 16 + l16) * 72 + ks * 32 + quad * 8];
            #pragma unroll
            for (int mf = 0; mf < 2; mf++)
                #pragma unroll
                for (int ks = 0; ks < 2; ks++)
                    Oacc[mf][nf] = __builtin_amdgcn_mfma_f32_16x16x32_bf16(pf[mf][ks], vf[ks], Oacc[mf][nf], 0, 0, 0);
        }
        __syncthreads();  // (C) done reading V half 0

        // stage V half 1: keys 64..127
        #pragma unroll
        for (int it = 0; it < 4; ++it) {
            int vid = it * 256 + tid;
            int d = vid >> 3, c8 = vid & 7;
            *(short8*)&Vs[d * 72 + c8 * 8] =
                *(const short8*)(vt + ((size_t)(b * AT_H + h) * 128 + d) * AT_T + kt * 128 + 64 + c8 * 8);
        }
        __syncthreads();  // (D)

        // ---- PV half 1 (keys 64..127) ----
        #pragma unroll
        for (int nf = 0; nf < 8; nf++) {
            short8 vf[2];
            #pragma unroll
            for (int ks = 0; ks < 2; ks++)
                vf[ks] = *(const short8*)&Vs[(nf * 16 + l16) * 72 + ks * 32 + quad * 8];
            #pragma unroll
            for (int mf = 0; mf < 2; mf++)
                #pragma unroll
                for (int ks = 0; ks < 2; ks++)
                    Oacc[mf][nf] = __builtin_amdgcn_mfma_f32_16x16x32_bf16(pf[mf][ks + 2], vf[ks], Oacc[mf][nf], 0, 0, 0);
        }
        __syncthreads();  // (B) before next iteration restages Ks/Vs (and Ks==Ps)
    }

    // ---- epilogue: O / l -> bf16 ----
    #pragma unroll
    for (int mf = 0; mf < 2; mf++)
        #pragma unroll
        for (int r = 0; r < 4; r++) {
            float inv = 1.0f / l_i[mf * 4 + r];
            int row = qt * 128 + wave * 32 + mf * 16 + quad * 4 + r;
            #pragma unroll
            for (int nf = 0; nf < 8; nf++) {
                size_t off = ((size_t)((b * AT_T + row) * AT_H) + h) * 128 + nf * 16 + l16;
                o[off] = f2bf(Oacc[mf][nf][r] * inv);
            }
        }
}

// ---------------- launch ----------------
extern "C" void kernel_launch(void* const* d_in, const int* in_sizes, int n_in,
                              void* d_out, int out_size, void* d_ws, size_t ws_size,
                              hipStream_t stream) {
    const float* x    = (const float*)d_in[0];
    const float* w_aq = (const float*)d_in[1];
    const float* w_ak = (const float*)d_in[2];
    const float* w_av = (const float*)d_in[3];
    const float* w_ao = (const float*)d_in[4];
    float* outp = (float*)d_out;

    // workspace layout (bf16 elements)
    u16* ws   = (u16*)d_ws;
    u16* xb   = ws;                    // [4096][2048]      x, bf16
    u16* wqb  = xb   + (size_t)NROW * HD;     // [2048 n][2048 k]  (w_aq^T per head)
    u16* wkb  = wqb  + (size_t)HD * AT_M;
    u16* wvb  = wkb  + (size_t)HD * AT_M;
    u16* waob = wvb  + (size_t)HD * AT_M;     // [2048 m][2048 hd] (w_ao^T)
    u16* qb   = waob + (size_t)HD * AT_M;     // [B,T,H,D]
    u16* kb   = qb   + (size_t)NROW * HD;
    u16* vb   = kb   + (size_t)NROW * HD;
    u16* vtb  = vb   + (size_t)NROW * HD;     // [B,H,D,T]
    u16* ob   = xb;                           // alias: xb dead after projections

    // 1) casts / transposes
    cast_bf16_k<<<(NROW * HD / 4 + 255) / 256, 256, 0, stream>>>(x, xb, NROW * HD / 4);
    dim3 tb(32, 8);
    tcast_k<<<dim3(AT_D / 32, AT_M / 32, AT_H), tb, 0, stream>>>(w_aq, wqb, AT_M, AT_D);
    tcast_k<<<dim3(AT_D / 32, AT_M / 32, AT_H), tb, 0, stream>>>(w_ak, wkb, AT_M, AT_D);
    tcast_k<<<dim3(AT_D / 32, AT_M / 32, AT_H), tb, 0, stream>>>(w_av, wvb, AT_M, AT_D);
    tcast_k<<<dim3(AT_M / 32, HD / 32, 1), tb, 0, stream>>>(w_ao, waob, HD, AT_M);

    // 2) projections (bf16 out)
    dim3 gg(HD / 128, NROW / 128);
    gemm_bt_k<0><<<gg, 256, 0, stream>>>(xb, wqb, qb, NROW, HD, AT_M);
    gemm_bt_k<0><<<gg, 256, 0, stream>>>(xb, wkb, kb, NROW, HD, AT_M);
    gemm_bt_k<0><<<gg, 256, 0, stream>>>(xb, wvb, vb, NROW, HD, AT_M);

    // 3) RoPE on q,k
    rope_k<<<(NROW * AT_H * 64 + 255) / 256, 256, 0, stream>>>(qb, kb, NROW * AT_H * 64);

    // 4) v -> [B,H,D,T]
    tbf16_k<<<dim3(HD / 32, AT_T / 32, AT_B), tb, 0, stream>>>(vb, vtb, AT_T, HD);

    // 5) attention
    attn_k<<<dim3(AT_T / 128, AT_H, AT_B), 256, 0, stream>>>(qb, kb, vtb, ob);

    // 6) output projection (fp32 out)
    gemm_bt_k<1><<<dim3(AT_M / 128, NROW / 128), 256, 0, stream>>>(ob, waob, outp, NROW, AT_M, HD);
}

// Round 2
// 418.630 us; speedup vs baseline: 1.2927x; 1.2927x over previous
//
#include <hip/hip_runtime.h>
#include <hip/hip_bf16.h>
#include <cmath>

typedef unsigned short u16;
typedef __attribute__((ext_vector_type(8))) short short8;
typedef __attribute__((ext_vector_type(4))) float f32x4;
typedef __attribute__((ext_vector_type(4))) unsigned short u16x4;

#define AT_B 2
#define AT_T 2048
#define AT_H 16
#define AT_D 128
#define AT_M 2048
#define NROW (AT_B*AT_T)   // 4096
#define HD   (AT_H*AT_D)   // 2048

__device__ __forceinline__ u16 f2bf(float f) {
    union { float f; unsigned u; } v; v.f = f;
    unsigned u = v.u;
    unsigned r = u + 0x7fffu + ((u >> 16) & 1u);
    return (u16)(r >> 16);
}
__device__ __forceinline__ float bf2f(u16 h) {
    union { unsigned u; float f; } v; v.u = ((unsigned)h) << 16;
    return v.f;
}
__device__ __forceinline__ unsigned pack_bf2(float a, float b) {
    __hip_bfloat162 t = __float22bfloat162_rn(make_float2(a, b));
    union { __hip_bfloat162 h; unsigned u; } v; v.h = t;
    return v.u;
}

// ---------------- elementwise cast fp32 -> bf16 (vec4) ----------------
__global__ void cast_bf16_k(const float* __restrict__ in, u16* __restrict__ out, int n4) {
    int i = blockIdx.x * 256 + threadIdx.x;
    if (i >= n4) return;
    float4 v = ((const float4*)in)[i];
    u16x4 o;
    o.x = f2bf(v.x); o.y = f2bf(v.y); o.z = f2bf(v.z); o.w = f2bf(v.w);
    ((u16x4*)out)[i] = o;
}

// ------------- batched transpose-cast: in[bz][R][C] fp32 -> out[bz][C][R] bf16 -------------
__global__ void tcast_k(const float* __restrict__ in, u16* __restrict__ out, int R, int C) {
    __shared__ float tile[32][33];
    int bx = blockIdx.x, by = blockIdx.y, bz = blockIdx.z;
    const float* ip = in + (size_t)bz * R * C;
    u16* op = out + (size_t)bz * R * C;
    int tx = threadIdx.x, ty = threadIdx.y;
    #pragma unroll
    for (int j = 0; j < 32; j += 8)
        tile[ty + j][tx] = ip[(size_t)(by * 32 + ty + j) * C + bx * 32 + tx];
    __syncthreads();
    #pragma unroll
    for (int j = 0; j < 32; j += 8)
        op[(size_t)(bx * 32 + ty + j) * R + by * 32 + tx] = f2bf(tile[tx][ty + j]);
}

// ------------- batched transpose bf16 -> bf16: in[bz][R][C] -> out[bz][C][R] -------------
__global__ void tbf16_k(const u16* __restrict__ in, u16* __restrict__ out, int R, int C) {
    __shared__ u16 tile[32][33];
    int bx = blockIdx.x, by = blockIdx.y, bz = blockIdx.z;
    const u16* ip = in + (size_t)bz * R * C;
    u16* op = out + (size_t)bz * R * C;
    int tx = threadIdx.x, ty = threadIdx.y;
    #pragma unroll
    for (int j = 0; j < 32; j += 8)
        tile[ty + j][tx] = ip[(size_t)(by * 32 + ty + j) * C + bx * 32 + tx];
    __syncthreads();
    #pragma unroll
    for (int j = 0; j < 32; j += 8)
        op[(size_t)(bx * 32 + ty + j) * R + by * 32 + tx] = tile[tx][ty + j];
}

// ---------------- RoPE in place; q additionally scaled by 1/128 (muP) ----------------
__global__ void rope_k(u16* __restrict__ q, u16* __restrict__ k, int total) {
    int i = blockIdx.x * 256 + threadIdx.x;
    if (i >= total) return;
    int d = i & 63;
    int rest = i >> 6;                 // (b*T+t)*H + h
    int t = (rest >> 4) & (AT_T - 1);
    size_t base = (size_t)rest * 128;
    float freq = __expf(-(float)d * (9.210340371976184f / 64.0f)); // 10000^{-d/64}
    float ang = (float)t * freq;
    float s, c;
    sincosf(ang, &s, &c);
    const float qs = 0.0078125f;  // 1/128, exact in bf16 scaling
    float qe = bf2f(q[base + d]), qo = bf2f(q[base + d + 64]);
    q[base + d]      = f2bf((qe * c - qo * s) * qs);
    q[base + d + 64] = f2bf((qe * s + qo * c) * qs);
    float ke = bf2f(k[base + d]), ko = bf2f(k[base + d + 64]);
    k[base + d]      = f2bf(ke * c - ko * s);
    k[base + d + 64] = f2bf(ke * s + ko * c);
}

// ---------------- GEMM: C[M][N] = A[M][K] * Bt[N][K]^T  (bf16 in, fp32 acc) ----------------
// m97 structure: 128x128 tile, BK=64, 4 waves each 64x64, global_load_lds width 16.
// SEGQKV: output columns segmented into 2048-wide arrays laid out back-to-back.
template<int FP32OUT, bool SEGQKV>
__global__ __launch_bounds__(256, 2) void gemm_bt_k(
    const u16* __restrict__ A, const u16* __restrict__ Bt, void* __restrict__ Cv,
    int M, int N, int K)
{
    __shared__ u16 As[128 * 64];
    __shared__ u16 Bs[128 * 64];
    const int tid = threadIdx.x, wave = tid >> 6, lane = tid & 63;
    const int quad = lane >> 4, l16 = lane & 15;
    const int m0 = blockIdx.y * 128, n0 = blockIdx.x * 128;
    const int mw = (wave & 1) * 64, nw = (wave >> 1) * 64;

    f32x4 zero = {0.f, 0.f, 0.f, 0.f};
    f32x4 acc[4][4];
    #pragma unroll
    for (int i = 0; i < 4; i++)
        #pragma unroll
        for (int j = 0; j < 4; j++) acc[i][j] = zero;

    const int srow = (lane >> 3);    // 0..7
    const int scol = (lane & 7) * 8; // ushort col within BK

    for (int kk = 0; kk < K; kk += 64) {
        #pragma unroll
        for (int c = 0; c < 4; c++) {
            int ci = wave * 4 + c;
            const u16* ga = A  + (size_t)(m0 + ci * 8 + srow) * K + kk + scol;
            const u16* gb = Bt + (size_t)(n0 + ci * 8 + srow) * K + kk + scol;
            __builtin_amdgcn_global_load_lds((const __attribute__((address_space(1))) void*)ga,
                                             (__attribute__((address_space(3))) void*)&As[ci * 512], 16, 0, 0);
            __builtin_amdgcn_global_load_lds((const __attribute__((address_space(1))) void*)gb,
                                             (__attribute__((address_space(3))) void*)&Bs[ci * 512], 16, 0, 0);
        }
        __syncthreads();
        #pragma unroll
        for (int ks = 0; ks < 2; ks++) {
            short8 af[4], bfr[4];
            #pragma unroll
            for (int mf = 0; mf < 4; mf++)
                af[mf] = *(const short8*)&As[(mw + mf * 16 + l16) * 64 + ks * 32 + quad * 8];
            #pragma unroll
            for (int nf = 0; nf < 4; nf++)
                bfr[nf] = *(const short8*)&Bs[(nw + nf * 16 + l16) * 64 + ks * 32 + quad * 8];
            #pragma unroll
            for (int mf = 0; mf < 4; mf++)
                #pragma unroll
                for (int nf = 0; nf < 4; nf++)
                    acc[mf][nf] = __builtin_amdgcn_mfma_f32_16x16x32_bf16(af[mf], bfr[nf], acc[mf][nf], 0, 0, 0);
        }
        __syncthreads();
    }
    // epilogue: C layout col=lane&15, row=quad*4+reg
    u16* cseg = 0;
    if (SEGQKV) cseg = (u16*)Cv + (size_t)(n0 >> 11) * M * 2048;
    #pragma unroll
    for (int mf = 0; mf < 4; mf++)
        #pragma unroll
        for (int nf = 0; nf < 4; nf++)
            #pragma unroll
            for (int r = 0; r < 4; r++) {
                int row = m0 + mw + mf * 16 + quad * 4 + r;
                int col = n0 + nw + nf * 16 + l16;
                if (SEGQKV)       cseg[(size_t)row * 2048 + (col & 2047)] = f2bf(acc[mf][nf][r]);
                else if (FP32OUT) ((float*)Cv)[(size_t)row * N + col] = acc[mf][nf][r];
                else              ((u16*) Cv)[(size_t)row * N + col] = f2bf(acc[mf][nf][r]);
            }
}

// ---------------- Flash attention, causal, paired complementary 64-row subtiles ----------------
// grid (16 pairs, H, B), 256 threads. q,k: [B,T,H,D] (q pre-scaled 1/128); vt: [B,H,D,T]; o: [B,T,H,D]
// Computes S^T = K.Q^T (softmax state at col=l16), O^T = V^T.P^T; P round-trip intra-wave.
__global__ __launch_bounds__(256, 2) void attn_k(
    const u16* __restrict__ q, const u16* __restrict__ k,
    const u16* __restrict__ vt, u16* __restrict__ o)
{
    __shared__ __align__(16) u16 Ks[64 * 132];   // [key][d], pad 4
    __shared__ __align__(16) u16 Vs[128 * 68];   // [d][key], pad 4 (= V^T)
    __shared__ __align__(16) u16 Pt[128 * 68];   // [qrow_local][key], pad 4 (= P, row-major)
    const int tid = threadIdx.x, wave = tid >> 6, lane = tid & 63;
    const int quad = lane >> 4, l16 = lane & 15;
    const int h = blockIdx.y, b = blockIdx.z;
    // b-flip swizzle: the 2 blocks a CU receives (ids 256 apart => b differs) get
    // complementary weights -> per-CU work constant.
    const int p = (b & 1) ? (15 - (int)blockIdx.x) : (int)blockIdx.x;
    const int sub0 = p, sub1 = 31 - p;
    const int nkt = 32 - p;            // 64-key tiles needed by subtile B

    // Q B-fragments direct from global
    short8 qf[2][4];
    #pragma unroll
    for (int mf = 0; mf < 2; mf++) {
        int row = (mf ? sub1 : sub0) * 64 + wave * 16 + l16;
        const u16* qp = q + ((size_t)(b * AT_T + row) * AT_H + h) * 128 + quad * 8;
        #pragma unroll
        for (int ks = 0; ks < 4; ks++)
            qf[mf][ks] = *(const short8*)(qp + ks * 32);
    }

    f32x4 zero = {0.f, 0.f, 0.f, 0.f};
    f32x4 Oacc[2][8];
    #pragma unroll
    for (int i = 0; i < 2; i++)
        #pragma unroll
        for (int j = 0; j < 8; j++) Oacc[i][j] = zero;
    float m_i[2] = {-1e30f, -1e30f}, l_i[2] = {0.f, 0.f};

    for (int kt = 0; kt < nkt; ++kt) {
        const bool actA = (kt <= sub0);
        // stage K tile: 64 keys x 128 d
        #pragma unroll
        for (int it = 0; it < 4; ++it) {
            int vid = it * 256 + tid;
            int key = vid >> 4, c8 = vid & 15;
            *(short8*)&Ks[key * 132 + c8 * 8] =
                *(const short8*)(k + ((size_t)(b * AT_T + kt * 64 + key) * AT_H + h) * 128 + c8 * 8);
        }
        // stage V^T tile: 128 d x 64 keys
        #pragma unroll
        for (int it = 0; it < 4; ++it) {
            int vid = it * 256 + tid;
            int d = vid >> 3, c8 = vid & 7;
            *(short8*)&Vs[d * 68 + c8 * 8] =
                *(const short8*)(vt + ((size_t)(b * AT_H + h) * 128 + d) * AT_T + kt * 64 + c8 * 8);
        }
        __syncthreads();   // (A) staging visible

        // ---- S^T = K . Q^T : tiles mt (16 keys) x mf (16 qrows) ----
        f32x4 St[4][2];
        #pragma unroll
        for (int mt = 0; mt < 4; mt++) { St[mt][0] = zero; St[mt][1] = zero; }
        #pragma unroll
        for (int mt = 0; mt < 4; mt++) {
            short8 af[4];
            #pragma unroll
            for (int ks = 0; ks < 4; ks++)
                af[ks] = *(const short8*)&Ks[(mt * 16 + l16) * 132 + ks * 32 + quad * 8];
            #pragma unroll
            for (int ks = 0; ks < 4; ks++)
                St[mt][1] = __builtin_amdgcn_mfma_f32_16x16x32_bf16(af[ks], qf[1][ks], St[mt][1], 0, 0, 0);
            if (actA) {
                #pragma unroll
                for (int ks = 0; ks < 4; ks++)
                    St[mt][0] = __builtin_amdgcn_mfma_f32_16x16x32_bf16(af[ks], qf[0][ks], St[mt][0], 0, 0, 0);
            }
        }

        // ---- online softmax per mf (lane owns qrow = col l16; keys at quad*4+r per mt) ----
        #pragma unroll
        for (int mf = 0; mf < 2; mf++) {
            if (mf == 0 && !actA) continue;
            const int sub = mf ? sub1 : sub0;
            if (kt == sub) {  // diagonal tile: mask
                int qrow = sub * 64 + wave * 16 + l16;
                #pragma unroll
                for (int mt = 0; mt < 4; mt++)
                    #pragma unroll
                    for (int r = 0; r < 4; r++) {
                        int key = kt * 64 + mt * 16 + quad * 4 + r;
                        if (key > qrow) St[mt][mf][r] = -1e30f;
                    }
            }
            float mloc = -1e30f;
            #pragma unroll
            for (int mt = 0; mt < 4; mt++)
                #pragma unroll
                for (int r = 0; r < 4; r++) mloc = fmaxf(mloc, St[mt][mf][r]);
            mloc = fmaxf(mloc, __shfl_xor(mloc, 16, 64));
            mloc = fmaxf(mloc, __shfl_xor(mloc, 32, 64));
            float mnew = fmaxf(m_i[mf], mloc);
            float al = __expf(m_i[mf] - mnew);
            m_i[mf] = mnew;
            float rs = 0.f;
            #pragma unroll
            for (int mt = 0; mt < 4; mt++)
                #pragma unroll
                for (int r = 0; r < 4; r++) {
                    float pv = __expf(St[mt][mf][r] - mnew);
                    St[mt][mf][r] = pv;
                    rs += pv;
                }
            rs += __shfl_xor(rs, 16, 64);
            rs += __shfl_xor(rs, 32, 64);
            l_i[mf] = l_i[mf] * al + rs;
            #pragma unroll
            for (int mt = 0; mt < 8; mt++)
                #pragma unroll
                for (int r = 0; r < 4; r++) Oacc[mf][mt][r] *= al;
            // pack P row (this lane's qrow), keys quad*4+r per mt -- intra-wave buffer
            u16* pp = &Pt[(mf * 64 + wave * 16 + l16) * 68 + quad * 4];
            #pragma unroll
            for (int mt = 0; mt < 4; mt++) {
                *(unsigned*)(pp + mt * 16)     = pack_bf2(St[mt][mf][0], St[mt][mf][1]);
                *(unsigned*)(pp + mt * 16 + 2) = pack_bf2(St[mt][mf][2], St[mt][mf][3]);
            }
        }

        // ---- O^T += V^T . P^T  (P read intra-wave; no barrier needed) ----
        #pragma unroll
        for (int ks = 0; ks < 2; ks++) {
            short8 pf1 = *(const short8*)&Pt[(64 + wave * 16 + l16) * 68 + ks * 32 + quad * 8];
            short8 pf0;
            if (actA) pf0 = *(const short8*)&Pt[(wave * 16 + l16) * 68 + ks * 32 + quad * 8];
            #pragma unroll
            for (int mt = 0; mt < 8; mt++) {
                short8 vf = *(const short8*)&Vs[(mt * 16 + l16) * 68 + ks * 32 + quad * 8];
                Oacc[1][mt] = __builtin_amdgcn_mfma_f32_16x16x32_bf16(vf, pf1, Oacc[1][mt], 0, 0, 0);
                if (actA)
                    Oacc[0][mt] = __builtin_amdgcn_mfma_f32_16x16x32_bf16(vf, pf0, Oacc[0][mt], 0, 0, 0);
            }
        }
        __syncthreads();   // (B) before next iteration restages Ks/Vs
    }

    // ---- epilogue: O^T lane col = own qrow; d = mt*16 + quad*4 + r ----
    #pragma unroll
    for (int mf = 0; mf < 2; mf++) {
        float inv = 1.0f / l_i[mf];
        int row = (mf ? sub1 : sub0) * 64 + wave * 16 + l16;
        u16* op = o + ((size_t)(b * AT_T + row) * AT_H + h) * 128 + quad * 4;
        #pragma unroll
        for (int mt = 0; mt < 8; mt++) {
            *(unsigned*)(op + mt * 16)     = pack_bf2(Oacc[mf][mt][0] * inv, Oacc[mf][mt][1] * inv);
            *(unsigned*)(op + mt * 16 + 2) = pack_bf2(Oacc[mf][mt][2] * inv, Oacc[mf][mt][3] * inv);
        }
    }
}

// ---------------- launch ----------------
extern "C" void kernel_launch(void* const* d_in, const int* in_sizes, int n_in,
                              void* d_out, int out_size, void* d_ws, size_t ws_size,
                              hipStream_t stream) {
    const float* x    = (const float*)d_in[0];
    const float* w_aq = (const float*)d_in[1];
    const float* w_ak = (const float*)d_in[2];
    const float* w_av = (const float*)d_in[3];
    const float* w_ao = (const float*)d_in[4];
    float* outp = (float*)d_out;

    // workspace layout (bf16 elements) -- wq/wk/wv and q/k/v deliberately contiguous
    u16* ws   = (u16*)d_ws;
    u16* xb   = ws;                           // [4096][2048]      x, bf16
    u16* wqb  = xb   + (size_t)NROW * HD;     // [6144 n][2048 k]  (wq|wk|wv transposed)
    u16* wkb  = wqb  + (size_t)HD * AT_M;
    u16* wvb  = wkb  + (size_t)HD * AT_M;
    u16* waob = wvb  + (size_t)HD * AT_M;     // [2048 m][2048 hd] (w_ao^T)
    u16* qb   = waob + (size_t)HD * AT_M;     // [B,T,H,D] (then kb, vb contiguous)
    u16* kb   = qb   + (size_t)NROW * HD;
    u16* vb   = kb   + (size_t)NROW * HD;
    u16* vtb  = vb   + (size_t)NROW * HD;     // [B,H,D,T]
    u16* ob   = xb;                           // alias: xb dead after projections

    // 1) casts / transposes
    cast_bf16_k<<<(NROW * HD / 4 + 255) / 256, 256, 0, stream>>>(x, xb, NROW * HD / 4);
    dim3 tb(32, 8);
    tcast_k<<<dim3(AT_D / 32, AT_M / 32, AT_H), tb, 0, stream>>>(w_aq, wqb, AT_M, AT_D);
    tcast_k<<<dim3(AT_D / 32, AT_M / 32, AT_H), tb, 0, stream>>>(w_ak, wkb, AT_M, AT_D);
    tcast_k<<<dim3(AT_D / 32, AT_M / 32, AT_H), tb, 0, stream>>>(w_av, wvb, AT_M, AT_D);
    tcast_k<<<dim3(AT_M / 32, HD / 32, 1), tb, 0, stream>>>(w_ao, waob, HD, AT_M);

    // 2) fused QKV projection: N = 6144, outputs segmented into qb|kb|vb
    gemm_bt_k<0, true><<<dim3(3 * HD / 128, NROW / 128), 256, 0, stream>>>(xb, wqb, qb, NROW, 3 * HD, AT_M);

    // 3) RoPE on q,k (q scaled by 1/128)
    rope_k<<<(NROW * AT_H * 64 + 255) / 256, 256, 0, stream>>>(qb, kb, NROW * AT_H * 64);

    // 4) v -> [B,H,D,T]
    tbf16_k<<<dim3(HD / 32, AT_T / 32, AT_B), tb, 0, stream>>>(vb, vtb, AT_T, HD);

    // 5) attention (paired complementary subtiles)
    attn_k<<<dim3(16, AT_H, AT_B), 256, 0, stream>>>(qb, kb, vtb, ob);

    // 6) output projection (fp32 out)
    gemm_bt_k<1, false><<<dim3(AT_M / 128, NROW / 128), 256, 0, stream>>>(ob, waob, outp, NROW, AT_M, HD);
}